// Round 2
// baseline (236.857 us; speedup 1.0000x reference)
//
#include <hip/hip_runtime.h>
#include <hip/hip_bf16.h>
#include <cstdint>

#define DIM   1024
#define KEY   128
#define UV    1024
#define NCOL  (UV*2 + KEY)   // 2176
#define SEQ   2048
#define BATCH 4
#define MTOT  (BATCH*SEQ)    // 8192
#define SCALE 0.08838834764831845f  // 1/sqrt(128)

typedef __attribute__((ext_vector_type(8))) short short8;
typedef __attribute__((ext_vector_type(4))) float f32x4;

__device__ inline unsigned short f2b(float x) {
  unsigned int u = __float_as_uint(x);
  unsigned int r = (u + 0x7fffu + ((u >> 16) & 1u)) >> 16;
  return (unsigned short)r;
}
__device__ inline float b2f(unsigned short x) {
  return __uint_as_float(((unsigned int)x) << 16);
}

__device__ inline void gload_lds16(const void* g, void* l) {
  __builtin_amdgcn_global_load_lds(
      (const __attribute__((address_space(1))) unsigned int*)g,
      (__attribute__((address_space(3))) unsigned int*)l, 16, 0, 0);
}

// ---------------------------------------------------------------------------
// 256x128 bt-GEMM tile, 8 waves (4M x 2N), BK=64, 3 LDS K-tile buffers,
// counted vmcnt prefetch (2 tiles deep), st-16B XOR swizzle, setprio MFMA.
// C[m][n] = sum_k A[m][k]*Bt[n][k].  K multiple of 64, K>=128.
// LDS: ldsA[3][256*64] + ldsB[3][128*64] bf16 = 147456 B dynamic.
// ---------------------------------------------------------------------------
__device__ __forceinline__ void gemm8w_256x128(
    const unsigned short* __restrict__ A, int lda,
    const unsigned short* __restrict__ Bt, int ldb,
    int K, f32x4 acc[4][4], unsigned short* lds) {
  const int tid  = threadIdx.x;
  const int lane = tid & 63;
  const int wid  = tid >> 6;      // 0..7
  const int wm   = wid >> 1;      // 0..3
  const int wn   = wid & 1;       // 0..1
  const int fr   = lane & 15;
  const int fq   = lane >> 4;

  unsigned short* ldsA = lds;               // 3 * 16384 elems
  unsigned short* ldsB = lds + 3 * 16384;   // 3 * 8192 elems

#pragma unroll
  for (int i = 0; i < 4; ++i)
#pragma unroll
    for (int j = 0; j < 4; ++j) acc[i][j] = (f32x4){0.f, 0.f, 0.f, 0.f};

  // stage one K-tile (t) into buffer b: A 4 rounds, B 2 rounds, 16B chunks.
  // swizzle: LDS chunk (r,q) holds global (r, q ^ ((r>>2)&3)).
  auto stage = [&](int t, int b) {
    const unsigned short* Ag = A + (size_t)t * 64;
    const unsigned short* Bg = Bt + (size_t)t * 64;
    unsigned short* la = ldsA + b * 16384;
    unsigned short* lb = ldsB + b * 8192;
#pragma unroll
    for (int p = 0; p < 4; ++p) {
      int c = p * 512 + tid, r = c >> 3, q = c & 7;
      int qs = q ^ ((r >> 2) & 3);
      gload_lds16(Ag + (size_t)r * lda + qs * 8, la + ((size_t)(p * 512 + wid * 64)) * 8);
    }
#pragma unroll
    for (int p = 0; p < 2; ++p) {
      int c = p * 512 + tid, r = c >> 3, q = c & 7;
      int qs = q ^ ((r >> 2) & 3);
      gload_lds16(Bg + (size_t)r * ldb + qs * 8, lb + ((size_t)(p * 512 + wid * 64)) * 8);
    }
  };

  const int swz   = (fr >> 2) & 3;
  const int colk0 = (fq ^ swz) * 8;          // kk=0 byte-col (elems); kk=1: +32
  const int rA    = (wm * 64 + fr) * 64;     // + i*1024
  const int rB    = (wn * 64 + fr) * 64;     // + j*1024

  const int NT = K >> 6;
  stage(0, 0);
  stage(1, 1);
  asm volatile("s_waitcnt vmcnt(6)" ::: "memory");   // tile0 landed; tile1 in flight
  __builtin_amdgcn_s_barrier();
  asm volatile("" ::: "memory");

  int cur = 0;
  for (int t = 0; t < NT; ++t) {
    unsigned short* la = ldsA + cur * 16384;
    unsigned short* lb = ldsB + cur * 8192;
    const int c2 = (cur >= 1) ? cur - 1 : 2;        // (cur+2)%3
    const bool more = (t + 2) < NT;
    if (more) stage(t + 2, c2);                     // buffer last read in iter t-1

    short8 af[4], bf[4];
    // ---- phase A: kk = 0 ----
#pragma unroll
    for (int i = 0; i < 4; ++i) af[i] = *(const short8*)&la[rA + i * 1024 + colk0];
#pragma unroll
    for (int j = 0; j < 4; ++j) bf[j] = *(const short8*)&lb[rB + j * 1024 + colk0];
    __builtin_amdgcn_s_barrier();
    asm volatile("" ::: "memory");
    __builtin_amdgcn_s_setprio(1);
#pragma unroll
    for (int i = 0; i < 4; ++i)
#pragma unroll
      for (int j = 0; j < 4; ++j)
        acc[i][j] = __builtin_amdgcn_mfma_f32_16x16x32_bf16(af[i], bf[j], acc[i][j], 0, 0, 0);
    __builtin_amdgcn_s_setprio(0);
    // ---- phase B: kk = 1 ----
#pragma unroll
    for (int i = 0; i < 4; ++i) af[i] = *(const short8*)&la[rA + i * 1024 + colk0 + 32];
#pragma unroll
    for (int j = 0; j < 4; ++j) bf[j] = *(const short8*)&lb[rB + j * 1024 + colk0 + 32];
    __builtin_amdgcn_s_barrier();
    asm volatile("" ::: "memory");
    __builtin_amdgcn_s_setprio(1);
#pragma unroll
    for (int i = 0; i < 4; ++i)
#pragma unroll
      for (int j = 0; j < 4; ++j)
        acc[i][j] = __builtin_amdgcn_mfma_f32_16x16x32_bf16(af[i], bf[j], acc[i][j], 0, 0, 0);
    __builtin_amdgcn_s_setprio(0);
    asm volatile("" ::: "memory");
    if (more) asm volatile("s_waitcnt vmcnt(6)" ::: "memory");   // tile t+1 landed
    else      asm volatile("s_waitcnt vmcnt(0)" ::: "memory");
    __builtin_amdgcn_s_barrier();
    asm volatile("" ::: "memory");
    cur = (cur == 2) ? 0 : cur + 1;
  }
}

// C/D mapping: row = wm*64 + i*16 + fq*4 + r ; col = wn*64 + j*16 + fr
#define EPILOGUE_COORDS()                      \
  const int lane = threadIdx.x & 63;           \
  const int wid  = threadIdx.x >> 6;           \
  const int wm   = wid >> 1, wn = wid & 1;     \
  const int fr   = lane & 15;                  \
  const int fq   = lane >> 4;

// ---------------------------------------------------------------------------
// helper kernels (unchanged from round 1)
// ---------------------------------------------------------------------------
__global__ __launch_bounds__(256) void k_cvt(const float* __restrict__ in,
                                             unsigned short* __restrict__ out) {
  int id = blockIdx.x * 256 + threadIdx.x;
  float4 f = ((const float4*)in)[id];
  ushort4 o;
  o.x = f2b(f.x); o.y = f2b(f.y); o.z = f2b(f.z); o.w = f2b(f.w);
  ((ushort4*)out)[id] = o;
}

__global__ void k_tcvt(const float* __restrict__ in, unsigned short* __restrict__ out,
                       int R, int C) {
  __shared__ float t[32][33];
  int c0 = blockIdx.x * 32, r0 = blockIdx.y * 32;
  int tx = threadIdx.x, ty = threadIdx.y;
#pragma unroll
  for (int i = 0; i < 4; ++i)
    t[ty + i * 8][tx] = in[(size_t)(r0 + ty + i * 8) * C + c0 + tx];
  __syncthreads();
#pragma unroll
  for (int i = 0; i < 4; ++i)
    out[(size_t)(c0 + ty + i * 8) * R + r0 + tx] = f2b(t[tx][ty + i * 8]);
}

__global__ __launch_bounds__(256) void k_masksum(const int* __restrict__ mask,
                                                 float* __restrict__ ll) {
  int wid = threadIdx.x >> 6, lane = threadIdx.x & 63;
  int row = blockIdx.x * 4 + wid;
  const int4* p = (const int4*)(mask + (size_t)row * SEQ);
  int s = 0;
#pragma unroll
  for (int i = 0; i < 8; ++i) { int4 v = p[lane + 64 * i]; s += v.x + v.y + v.z + v.w; }
  for (int off = 32; off; off >>= 1) s += __shfl_down(s, off);
  if (lane == 0) ll[row] = (float)s;
}

__global__ __launch_bounds__(256) void k_rope(const float* __restrict__ qk,
                                              const float* __restrict__ sn,
                                              const float* __restrict__ cs,
                                              const float* __restrict__ qg,
                                              const float* __restrict__ qb,
                                              const float* __restrict__ kg,
                                              const float* __restrict__ kb,
                                              unsigned short* __restrict__ q,
                                              unsigned short* __restrict__ k) {
  int id = blockIdx.x * 256 + threadIdx.x;
  int m = id >> 6, t = id & 63;
  int n = m & (SEQ - 1);
  float x1 = qk[m * KEY + 2 * t], x2 = qk[m * KEY + 2 * t + 1];
  float s_ = sn[n * 64 + t], c_ = cs[n * 64 + t];
  float a1 = x1 * qg[2 * t] + qb[2 * t];
  float a2 = x2 * qg[2 * t + 1] + qb[2 * t + 1];
  q[m * KEY + t]      = f2b(a1 * c_ - a2 * s_);
  q[m * KEY + 64 + t] = f2b(a1 * s_ + a2 * c_);
  float b1 = x1 * kg[2 * t] + kb[2 * t];
  float b2 = x2 * kg[2 * t + 1] + kb[2 * t + 1];
  k[m * KEY + t]      = f2b(b1 * c_ - b2 * s_);
  k[m * KEY + 64 + t] = f2b(b1 * s_ + b2 * c_);
}

__global__ __launch_bounds__(256) void k_vT(const unsigned short* __restrict__ v,
                                            unsigned short* __restrict__ vT) {
  __shared__ unsigned short t[64][65];
  int b = blockIdx.z;
  int n0 = blockIdx.x * 64;
  int d0 = blockIdx.y * 64;
  int tid = threadIdx.x;
  int r = tid >> 4;
  int c4 = (tid & 15) * 4;
#pragma unroll
  for (int i = 0; i < 4; ++i) {
    int n = n0 + r + i * 16;
    ushort4 val = *(const ushort4*)&v[((size_t)b * SEQ + n) * UV + d0 + c4];
    t[c4 + 0][r + i * 16] = val.x;
    t[c4 + 1][r + i * 16] = val.y;
    t[c4 + 2][r + i * 16] = val.z;
    t[c4 + 3][r + i * 16] = val.w;
  }
  __syncthreads();
#pragma unroll
  for (int i = 0; i < 4; ++i) {
    int d = d0 + r + i * 16;
    ushort4 o;
    o.x = t[r + i * 16][c4 + 0];
    o.y = t[r + i * 16][c4 + 1];
    o.z = t[r + i * 16][c4 + 2];
    o.w = t[r + i * 16][c4 + 3];
    *(ushort4*)&vT[((size_t)b * UV + d) * SEQ + n0 + c4] = o;
  }
}

// ---------------------------------------------------------------------------
// GEMM kernels (256x128 tiles, 512 threads)
// ---------------------------------------------------------------------------
#define LDS_BYTES 147456

__global__ __launch_bounds__(512, 2) void k_gemm1(const unsigned short* __restrict__ hbf,
                                                  const unsigned short* __restrict__ WiT,
                                                  const float* __restrict__ bi,
                                                  unsigned short* __restrict__ u,
                                                  unsigned short* __restrict__ v,
                                                  float* __restrict__ qk) {
  extern __shared__ unsigned short lds[];
  int m0 = blockIdx.x * 256, n0 = blockIdx.y * 128;
  f32x4 acc[4][4];
  gemm8w_256x128(hbf + (size_t)m0 * DIM, DIM, WiT + (size_t)n0 * DIM, DIM, DIM, acc, lds);
  EPILOGUE_COORDS();
#pragma unroll
  for (int i = 0; i < 4; ++i)
#pragma unroll
    for (int j = 0; j < 4; ++j)
#pragma unroll
      for (int r = 0; r < 4; ++r) {
        int row = m0 + wm * 64 + i * 16 + fq * 4 + r;
        int col = n0 + wn * 64 + j * 16 + fr;
        float x = acc[i][j][r] + bi[col];
        float s = x / (1.f + __expf(-x));
        if (n0 < UV)            u[(size_t)row * UV + col] = f2b(s);
        else if (n0 < 2 * UV)   v[(size_t)row * UV + col - UV] = f2b(s);
        else                    qk[(size_t)row * KEY + col - 2 * UV] = s;
      }
}

__global__ __launch_bounds__(512, 2) void k_qk(const unsigned short* __restrict__ q,
                                               const unsigned short* __restrict__ k,
                                               const int* __restrict__ mask,
                                               const float* __restrict__ ll,
                                               unsigned short* __restrict__ Abuf) {
  extern __shared__ unsigned short lds[];
  int b = blockIdx.z;
  int m0 = blockIdx.x * 256, n0 = blockIdx.y * 128;
  f32x4 acc[4][4];
  gemm8w_256x128(q + ((size_t)b * SEQ + m0) * KEY, KEY,
                 k + ((size_t)b * SEQ + n0) * KEY, KEY, KEY, acc, lds);
  EPILOGUE_COORDS();
#pragma unroll
  for (int i = 0; i < 4; ++i)
#pragma unroll
    for (int j = 0; j < 4; ++j)
#pragma unroll
      for (int r = 0; r < 4; ++r) {
        int row = m0 + wm * 64 + i * 16 + fq * 4 + r;
        int col = n0 + wn * 64 + j * 16 + fr;
        float a = acc[i][j][r] * SCALE;
        int mk = mask[((size_t)b * SEQ + row) * SEQ + col];
        float rel = (mk != 0 && a > 0.f) ? a : 0.f;
        float Av = rel * rel / ll[b * SEQ + row];
        Abuf[((size_t)b * SEQ + row) * SEQ + col] = f2b(Av);
      }
}

__global__ __launch_bounds__(512, 2) void k_av(const unsigned short* __restrict__ Abuf,
                                               const unsigned short* __restrict__ vT,
                                               const unsigned short* __restrict__ u,
                                               unsigned short* __restrict__ g) {
  extern __shared__ unsigned short lds[];
  int b = blockIdx.z;
  int m0 = blockIdx.x * 256, n0 = blockIdx.y * 128;
  f32x4 acc[4][4];
  gemm8w_256x128(Abuf + ((size_t)b * SEQ + m0) * SEQ, SEQ,
                 vT + ((size_t)b * UV + n0) * SEQ, SEQ, SEQ, acc, lds);
  EPILOGUE_COORDS();
#pragma unroll
  for (int i = 0; i < 4; ++i)
#pragma unroll
    for (int j = 0; j < 4; ++j)
#pragma unroll
      for (int r = 0; r < 4; ++r) {
        int row = m0 + wm * 64 + i * 16 + fq * 4 + r;
        int col = n0 + wn * 64 + j * 16 + fr;
        size_t gi = ((size_t)b * SEQ + row) * UV + col;
        g[gi] = f2b(acc[i][j][r] * b2f(u[gi]));
      }
}

__global__ __launch_bounds__(512, 2) void k_out(const unsigned short* __restrict__ g,
                                                const unsigned short* __restrict__ WoT,
                                                const float* __restrict__ bo,
                                                float* __restrict__ out) {
  extern __shared__ unsigned short lds[];
  int m0 = blockIdx.x * 256, n0 = blockIdx.y * 128;
  f32x4 acc[4][4];
  gemm8w_256x128(g + (size_t)m0 * UV, UV, WoT + (size_t)n0 * UV, UV, UV, acc, lds);
  EPILOGUE_COORDS();
#pragma unroll
  for (int i = 0; i < 4; ++i)
#pragma unroll
    for (int j = 0; j < 4; ++j)
#pragma unroll
      for (int r = 0; r < 4; ++r) {
        int row = m0 + wm * 64 + i * 16 + fq * 4 + r;
        int col = n0 + wn * 64 + j * 16 + fr;
        out[(size_t)row * DIM + col] = acc[i][j][r] + bo[col];
      }
}

// ---------------------------------------------------------------------------
extern "C" void kernel_launch(void* const* d_in, const int* in_sizes, int n_in,
                              void* d_out, int out_size, void* d_ws, size_t ws_size,
                              hipStream_t stream) {
  const float* h    = (const float*)d_in[0];
  const int*   mask = (const int*)d_in[1];
  const float* sn   = (const float*)d_in[2];
  const float* cs   = (const float*)d_in[3];
  const float* Wi   = (const float*)d_in[4];
  const float* bi   = (const float*)d_in[5];
  const float* Wo   = (const float*)d_in[6];
  const float* bo   = (const float*)d_in[7];
  const float* qg   = (const float*)d_in[8];
  const float* qb   = (const float*)d_in[9];
  const float* kg   = (const float*)d_in[10];
  const float* kb   = (const float*)d_in[11];
  float* out = (float*)d_out;

  static_assert(LDS_BYTES == (3 * 16384 + 3 * 8192) * 2, "lds size");
  hipFuncSetAttribute((const void*)k_gemm1, hipFuncAttributeMaxDynamicSharedMemorySize, LDS_BYTES);
  hipFuncSetAttribute((const void*)k_qk,    hipFuncAttributeMaxDynamicSharedMemorySize, LDS_BYTES);
  hipFuncSetAttribute((const void*)k_av,    hipFuncAttributeMaxDynamicSharedMemorySize, LDS_BYTES);
  hipFuncSetAttribute((const void*)k_out,   hipFuncAttributeMaxDynamicSharedMemorySize, LDS_BYTES);

  char* ws = (char*)d_ws;
  size_t off = 0;
  auto alloc = [&](size_t bytes) { void* p = ws + off; off += (bytes + 255) & ~(size_t)255; return p; };
  unsigned short* hbf  = (unsigned short*)alloc((size_t)MTOT * DIM * 2);
  unsigned short* WiT  = (unsigned short*)alloc((size_t)NCOL * DIM * 2);
  unsigned short* WoT  = (unsigned short*)alloc((size_t)DIM * UV * 2);
  unsigned short* u    = (unsigned short*)alloc((size_t)MTOT * UV * 2);
  unsigned short* v    = (unsigned short*)alloc((size_t)MTOT * UV * 2);
  unsigned short* vT   = (unsigned short*)alloc((size_t)MTOT * UV * 2);
  float*          qkb  = (float*)alloc((size_t)MTOT * KEY * 4);
  unsigned short* qbuf = (unsigned short*)alloc((size_t)MTOT * KEY * 2);
  unsigned short* kbuf = (unsigned short*)alloc((size_t)MTOT * KEY * 2);
  float*          ll   = (float*)alloc((size_t)MTOT * 4);
  unsigned short* Abuf = (unsigned short*)alloc((size_t)BATCH * SEQ * SEQ * 2);
  unsigned short* g    = (unsigned short*)alloc((size_t)MTOT * UV * 2);

  k_cvt<<<(MTOT * DIM / 4) / 256, 256, 0, stream>>>(h, hbf);
  k_tcvt<<<dim3(NCOL / 32, DIM / 32), dim3(32, 8), 0, stream>>>(Wi, WiT, DIM, NCOL);
  k_tcvt<<<dim3(UV / 32, DIM / 32), dim3(32, 8), 0, stream>>>(Wo, WoT, DIM, UV);
  k_masksum<<<MTOT / 4, 256, 0, stream>>>(mask, ll);

  k_gemm1<<<dim3(MTOT / 256, NCOL / 128), 512, LDS_BYTES, stream>>>(hbf, WiT, bi, u, v, qkb);
  k_rope<<<(MTOT * 64) / 256, 256, 0, stream>>>(qkb, sn, cs, qg, qb, kg, kb, qbuf, kbuf);
  k_vT<<<dim3(SEQ / 64, UV / 64, BATCH), 256, 0, stream>>>(v, vT);
  k_qk<<<dim3(SEQ / 256, SEQ / 128, BATCH), 512, LDS_BYTES, stream>>>(qbuf, kbuf, mask, ll, Abuf);
  k_av<<<dim3(SEQ / 256, UV / 128, BATCH), 512, LDS_BYTES, stream>>>(Abuf, vT, u, g);
  k_out<<<dim3(MTOT / 256, DIM / 128), 512, LDS_BYTES, stream>>>(g, WoT, bo, out);
}

// Round 3
// 205.053 us; speedup vs baseline: 1.1551x; 1.1551x over previous
//
#include <hip/hip_runtime.h>
#include <hip/hip_bf16.h>
#include <cstdint>

#define DIM   1024
#define KEY   128
#define UV    1024
#define NCOL  (UV*2 + KEY)   // 2176
#define SEQ   2048
#define BATCH 4
#define MTOT  (BATCH*SEQ)    // 8192
#define SCALE 0.08838834764831845f  // 1/sqrt(128)

typedef __attribute__((ext_vector_type(8))) short short8;
typedef __attribute__((ext_vector_type(4))) float f32x4;

__device__ inline unsigned short f2b(float x) {
  unsigned int u = __float_as_uint(x);
  unsigned int r = (u + 0x7fffu + ((u >> 16) & 1u)) >> 16;
  return (unsigned short)r;
}
__device__ inline float b2f(unsigned short x) {
  return __uint_as_float(((unsigned int)x) << 16);
}

__device__ inline void gload_lds16(const void* g, void* l) {
  __builtin_amdgcn_global_load_lds(
      (const __attribute__((address_space(1))) unsigned int*)g,
      (__attribute__((address_space(3))) unsigned int*)l, 16, 0, 0);
}

// ---------------------------------------------------------------------------
// 256x128 bt-GEMM tile, 8 waves (4M x 2N), BK=64, 3 LDS K-tile buffers,
// counted vmcnt prefetch (2 tiles deep), full 8-slot XOR swizzle
// (LDS(r,q) = global(r, q^(r&7)), 16B slots), setprio around MFMA.
// C[m][n] = sum_k A[m][k]*Bt[n][k].  K multiple of 64, K>=128.
// LDS: ldsA[3][256*64] + ldsB[3][128*64] bf16 = 147456 B dynamic.
// ---------------------------------------------------------------------------
__device__ __forceinline__ void gemm8w_256x128(
    const unsigned short* __restrict__ A, int lda,
    const unsigned short* __restrict__ Bt, int ldb,
    int K, f32x4 acc[4][4], unsigned short* lds) {
  const int tid  = threadIdx.x;
  const int lane = tid & 63;
  const int wid  = tid >> 6;      // 0..7
  const int wm   = wid >> 1;      // 0..3
  const int wn   = wid & 1;       // 0..1
  const int fr   = lane & 15;
  const int fq   = lane >> 4;

  unsigned short* ldsA = lds;               // 3 * 16384 elems
  unsigned short* ldsB = lds + 3 * 16384;   // 3 * 8192 elems

#pragma unroll
  for (int i = 0; i < 4; ++i)
#pragma unroll
    for (int j = 0; j < 4; ++j) acc[i][j] = (f32x4){0.f, 0.f, 0.f, 0.f};

  // stage one K-tile (t) into buffer b: A 4 rounds, B 2 rounds, 16B chunks.
  // LDS dest is linear; global source pre-swizzled: LDS(r,q) = G(r, q^(r&7)).
  auto stage = [&](int t, int b) {
    const unsigned short* Ag = A + (size_t)t * 64;
    const unsigned short* Bg = Bt + (size_t)t * 64;
    unsigned short* la = ldsA + b * 16384;
    unsigned short* lb = ldsB + b * 8192;
#pragma unroll
    for (int p = 0; p < 4; ++p) {
      int c = p * 512 + tid, r = c >> 3, q = c & 7;
      int qs = q ^ (r & 7);
      gload_lds16(Ag + (size_t)r * lda + qs * 8, la + ((size_t)(p * 512 + wid * 64)) * 8);
    }
#pragma unroll
    for (int p = 0; p < 2; ++p) {
      int c = p * 512 + tid, r = c >> 3, q = c & 7;
      int qs = q ^ (r & 7);
      gload_lds16(Bg + (size_t)r * ldb + qs * 8, lb + ((size_t)(p * 512 + wid * 64)) * 8);
    }
  };

  // read: natural slot for kk is (fq + 4*kk); stored at slot ^ (row&7),
  // row&7 == fr&7 for all fragment rows (i*16, wm*64, j*16, wn*64 are mult of 8).
  const int colk0 = ((fq ^ (fr & 7)) * 8);   // kk=0; kk=1 is colk0 ^ 32
  const int rA    = (wm * 64 + fr) * 64;     // + i*1024
  const int rB    = (wn * 64 + fr) * 64;     // + j*1024

  const int NT = K >> 6;
  stage(0, 0);
  stage(1, 1);
  asm volatile("s_waitcnt vmcnt(6)" ::: "memory");   // tile0 landed; tile1 in flight
  __builtin_amdgcn_s_barrier();
  asm volatile("" ::: "memory");

  int cur = 0;
  for (int t = 0; t < NT; ++t) {
    unsigned short* la = ldsA + cur * 16384;
    unsigned short* lb = ldsB + cur * 8192;
    const int c2 = (cur >= 1) ? cur - 1 : 2;        // (cur+2)%3
    const bool more = (t + 2) < NT;
    if (more) stage(t + 2, c2);                     // buffer last read in iter t-1

    short8 af[4], bf[4];
    // ---- phase A: kk = 0 ----
#pragma unroll
    for (int i = 0; i < 4; ++i) af[i] = *(const short8*)&la[rA + i * 1024 + colk0];
#pragma unroll
    for (int j = 0; j < 4; ++j) bf[j] = *(const short8*)&lb[rB + j * 1024 + colk0];
    __builtin_amdgcn_s_barrier();
    asm volatile("" ::: "memory");
    __builtin_amdgcn_s_setprio(1);
#pragma unroll
    for (int i = 0; i < 4; ++i)
#pragma unroll
      for (int j = 0; j < 4; ++j)
        acc[i][j] = __builtin_amdgcn_mfma_f32_16x16x32_bf16(af[i], bf[j], acc[i][j], 0, 0, 0);
    __builtin_amdgcn_s_setprio(0);
    // ---- phase B: kk = 1 ----
#pragma unroll
    for (int i = 0; i < 4; ++i) af[i] = *(const short8*)&la[rA + i * 1024 + (colk0 ^ 32)];
#pragma unroll
    for (int j = 0; j < 4; ++j) bf[j] = *(const short8*)&lb[rB + j * 1024 + (colk0 ^ 32)];
    __builtin_amdgcn_s_barrier();
    asm volatile("" ::: "memory");
    __builtin_amdgcn_s_setprio(1);
#pragma unroll
    for (int i = 0; i < 4; ++i)
#pragma unroll
      for (int j = 0; j < 4; ++j)
        acc[i][j] = __builtin_amdgcn_mfma_f32_16x16x32_bf16(af[i], bf[j], acc[i][j], 0, 0, 0);
    __builtin_amdgcn_s_setprio(0);
    asm volatile("" ::: "memory");
    if (more) asm volatile("s_waitcnt vmcnt(6)" ::: "memory");   // tile t+1 landed
    else      asm volatile("s_waitcnt vmcnt(0)" ::: "memory");
    __builtin_amdgcn_s_barrier();
    asm volatile("" ::: "memory");
    cur = (cur == 2) ? 0 : cur + 1;
  }
}

// C/D mapping: row = wm*64 + i*16 + fq*4 + r ; col = wn*64 + j*16 + fr
#define EPILOGUE_COORDS()                      \
  const int lane = threadIdx.x & 63;           \
  const int wid  = threadIdx.x >> 6;           \
  const int wm   = wid >> 1, wn = wid & 1;     \
  const int fr   = lane & 15;                  \
  const int fq   = lane >> 4;

// ---------------------------------------------------------------------------
// helper kernels
// ---------------------------------------------------------------------------
__global__ __launch_bounds__(256) void k_cvt(const float* __restrict__ in,
                                             unsigned short* __restrict__ out) {
  int id = blockIdx.x * 256 + threadIdx.x;
  float4 f = ((const float4*)in)[id];
  ushort4 o;
  o.x = f2b(f.x); o.y = f2b(f.y); o.z = f2b(f.z); o.w = f2b(f.w);
  ((ushort4*)out)[id] = o;
}

__global__ void k_tcvt(const float* __restrict__ in, unsigned short* __restrict__ out,
                       int R, int C) {
  __shared__ float t[32][33];
  int c0 = blockIdx.x * 32, r0 = blockIdx.y * 32;
  int tx = threadIdx.x, ty = threadIdx.y;
#pragma unroll
  for (int i = 0; i < 4; ++i)
    t[ty + i * 8][tx] = in[(size_t)(r0 + ty + i * 8) * C + c0 + tx];
  __syncthreads();
#pragma unroll
  for (int i = 0; i < 4; ++i)
    out[(size_t)(c0 + ty + i * 8) * R + r0 + tx] = f2b(t[tx][ty + i * 8]);
}

__global__ __launch_bounds__(256) void k_masksum(const int* __restrict__ mask,
                                                 float* __restrict__ ll) {
  int wid = threadIdx.x >> 6, lane = threadIdx.x & 63;
  int row = blockIdx.x * 4 + wid;
  const int4* p = (const int4*)(mask + (size_t)row * SEQ);
  int s = 0;
#pragma unroll
  for (int i = 0; i < 8; ++i) { int4 v = p[lane + 64 * i]; s += v.x + v.y + v.z + v.w; }
  for (int off = 32; off; off >>= 1) s += __shfl_down(s, off);
  if (lane == 0) ll[row] = (float)s;
}

__global__ __launch_bounds__(256) void k_rope(const float* __restrict__ qk,
                                              const float* __restrict__ sn,
                                              const float* __restrict__ cs,
                                              const float* __restrict__ qg,
                                              const float* __restrict__ qb,
                                              const float* __restrict__ kg,
                                              const float* __restrict__ kb,
                                              unsigned short* __restrict__ q,
                                              unsigned short* __restrict__ k) {
  int id = blockIdx.x * 256 + threadIdx.x;
  int m = id >> 6, t = id & 63;
  int n = m & (SEQ - 1);
  float x1 = qk[m * KEY + 2 * t], x2 = qk[m * KEY + 2 * t + 1];
  float s_ = sn[n * 64 + t], c_ = cs[n * 64 + t];
  float a1 = x1 * qg[2 * t] + qb[2 * t];
  float a2 = x2 * qg[2 * t + 1] + qb[2 * t + 1];
  q[m * KEY + t]      = f2b(a1 * c_ - a2 * s_);
  q[m * KEY + 64 + t] = f2b(a1 * s_ + a2 * c_);
  float b1 = x1 * kg[2 * t] + kb[2 * t];
  float b2 = x2 * kg[2 * t + 1] + kb[2 * t + 1];
  k[m * KEY + t]      = f2b(b1 * c_ - b2 * s_);
  k[m * KEY + 64 + t] = f2b(b1 * s_ + b2 * c_);
}

__global__ __launch_bounds__(256) void k_vT(const unsigned short* __restrict__ v,
                                            unsigned short* __restrict__ vT) {
  __shared__ unsigned short t[64][65];
  int b = blockIdx.z;
  int n0 = blockIdx.x * 64;
  int d0 = blockIdx.y * 64;
  int tid = threadIdx.x;
  int r = tid >> 4;
  int c4 = (tid & 15) * 4;
#pragma unroll
  for (int i = 0; i < 4; ++i) {
    int n = n0 + r + i * 16;
    ushort4 val = *(const ushort4*)&v[((size_t)b * SEQ + n) * UV + d0 + c4];
    t[c4 + 0][r + i * 16] = val.x;
    t[c4 + 1][r + i * 16] = val.y;
    t[c4 + 2][r + i * 16] = val.z;
    t[c4 + 3][r + i * 16] = val.w;
  }
  __syncthreads();
#pragma unroll
  for (int i = 0; i < 4; ++i) {
    int d = d0 + r + i * 16;
    ushort4 o;
    o.x = t[r + i * 16][c4 + 0];
    o.y = t[r + i * 16][c4 + 1];
    o.z = t[r + i * 16][c4 + 2];
    o.w = t[r + i * 16][c4 + 3];
    *(ushort4*)&vT[((size_t)b * UV + d) * SEQ + n0 + c4] = o;
  }
}

// ---------------------------------------------------------------------------
// GEMM kernels (256x128 tiles, 512 threads)
// ---------------------------------------------------------------------------
#define LDS_BYTES 147456

__global__ __launch_bounds__(512, 2) void k_gemm1(const unsigned short* __restrict__ hbf,
                                                  const unsigned short* __restrict__ WiT,
                                                  const float* __restrict__ bi,
                                                  unsigned short* __restrict__ u,
                                                  unsigned short* __restrict__ v,
                                                  float* __restrict__ qk) {
  extern __shared__ unsigned short lds[];
  int m0 = blockIdx.x * 256, n0 = blockIdx.y * 128;
  f32x4 acc[4][4];
  gemm8w_256x128(hbf + (size_t)m0 * DIM, DIM, WiT + (size_t)n0 * DIM, DIM, DIM, acc, lds);
  EPILOGUE_COORDS();
#pragma unroll
  for (int i = 0; i < 4; ++i)
#pragma unroll
    for (int j = 0; j < 4; ++j)
#pragma unroll
      for (int r = 0; r < 4; ++r) {
        int row = m0 + wm * 64 + i * 16 + fq * 4 + r;
        int col = n0 + wn * 64 + j * 16 + fr;
        float x = acc[i][j][r] + bi[col];
        float s = x / (1.f + __expf(-x));
        if (n0 < UV)            u[(size_t)row * UV + col] = f2b(s);
        else if (n0 < 2 * UV)   v[(size_t)row * UV + col - UV] = f2b(s);
        else                    qk[(size_t)row * KEY + col - 2 * UV] = s;
      }
}

__global__ __launch_bounds__(512, 2) void k_qk(const unsigned short* __restrict__ q,
                                               const unsigned short* __restrict__ k,
                                               const int* __restrict__ mask,
                                               const float* __restrict__ ll,
                                               unsigned short* __restrict__ Abuf) {
  extern __shared__ unsigned short lds[];
  int b = blockIdx.z;
  int m0 = blockIdx.x * 256, n0 = blockIdx.y * 128;
  f32x4 acc[4][4];
  gemm8w_256x128(q + ((size_t)b * SEQ + m0) * KEY, KEY,
                 k + ((size_t)b * SEQ + n0) * KEY, KEY, KEY, acc, lds);
  EPILOGUE_COORDS();
#pragma unroll
  for (int i = 0; i < 4; ++i)
#pragma unroll
    for (int j = 0; j < 4; ++j)
#pragma unroll
      for (int r = 0; r < 4; ++r) {
        int row = m0 + wm * 64 + i * 16 + fq * 4 + r;
        int col = n0 + wn * 64 + j * 16 + fr;
        float a = acc[i][j][r] * SCALE;
        int mk = mask[((size_t)b * SEQ + row) * SEQ + col];
        float rel = (mk != 0 && a > 0.f) ? a : 0.f;
        float Av = rel * rel / ll[b * SEQ + row];
        Abuf[((size_t)b * SEQ + row) * SEQ + col] = f2b(Av);
      }
}

__global__ __launch_bounds__(512, 2) void k_av(const unsigned short* __restrict__ Abuf,
                                               const unsigned short* __restrict__ vT,
                                               const unsigned short* __restrict__ u,
                                               unsigned short* __restrict__ g) {
  extern __shared__ unsigned short lds[];
  int b = blockIdx.z;
  int m0 = blockIdx.x * 256, n0 = blockIdx.y * 128;
  f32x4 acc[4][4];
  gemm8w_256x128(Abuf + ((size_t)b * SEQ + m0) * SEQ, SEQ,
                 vT + ((size_t)b * UV + n0) * SEQ, SEQ, SEQ, acc, lds);
  EPILOGUE_COORDS();
#pragma unroll
  for (int i = 0; i < 4; ++i)
#pragma unroll
    for (int j = 0; j < 4; ++j)
#pragma unroll
      for (int r = 0; r < 4; ++r) {
        int row = m0 + wm * 64 + i * 16 + fq * 4 + r;
        int col = n0 + wn * 64 + j * 16 + fr;
        size_t gi = ((size_t)b * SEQ + row) * UV + col;
        g[gi] = f2b(acc[i][j][r] * b2f(u[gi]));
      }
}

__global__ __launch_bounds__(512, 2) void k_out(const unsigned short* __restrict__ g,
                                                const unsigned short* __restrict__ WoT,
                                                const float* __restrict__ bo,
                                                float* __restrict__ out) {
  extern __shared__ unsigned short lds[];
  int m0 = blockIdx.x * 256, n0 = blockIdx.y * 128;
  f32x4 acc[4][4];
  gemm8w_256x128(g + (size_t)m0 * UV, UV, WoT + (size_t)n0 * UV, UV, UV, acc, lds);
  EPILOGUE_COORDS();
#pragma unroll
  for (int i = 0; i < 4; ++i)
#pragma unroll
    for (int j = 0; j < 4; ++j)
#pragma unroll
      for (int r = 0; r < 4; ++r) {
        int row = m0 + wm * 64 + i * 16 + fq * 4 + r;
        int col = n0 + wn * 64 + j * 16 + fr;
        out[(size_t)row * DIM + col] = acc[i][j][r] + bo[col];
      }
}

// ---------------------------------------------------------------------------
extern "C" void kernel_launch(void* const* d_in, const int* in_sizes, int n_in,
                              void* d_out, int out_size, void* d_ws, size_t ws_size,
                              hipStream_t stream) {
  const float* h    = (const float*)d_in[0];
  const int*   mask = (const int*)d_in[1];
  const float* sn   = (const float*)d_in[2];
  const float* cs   = (const float*)d_in[3];
  const float* Wi   = (const float*)d_in[4];
  const float* bi   = (const float*)d_in[5];
  const float* Wo   = (const float*)d_in[6];
  const float* bo   = (const float*)d_in[7];
  const float* qg   = (const float*)d_in[8];
  const float* qb   = (const float*)d_in[9];
  const float* kg   = (const float*)d_in[10];
  const float* kb   = (const float*)d_in[11];
  float* out = (float*)d_out;

  static_assert(LDS_BYTES == (3 * 16384 + 3 * 8192) * 2, "lds size");
  hipFuncSetAttribute((const void*)k_gemm1, hipFuncAttributeMaxDynamicSharedMemorySize, LDS_BYTES);
  hipFuncSetAttribute((const void*)k_qk,    hipFuncAttributeMaxDynamicSharedMemorySize, LDS_BYTES);
  hipFuncSetAttribute((const void*)k_av,    hipFuncAttributeMaxDynamicSharedMemorySize, LDS_BYTES);
  hipFuncSetAttribute((const void*)k_out,   hipFuncAttributeMaxDynamicSharedMemorySize, LDS_BYTES);

  char* ws = (char*)d_ws;
  size_t off = 0;
  auto alloc = [&](size_t bytes) { void* p = ws + off; off += (bytes + 255) & ~(size_t)255; return p; };
  unsigned short* hbf  = (unsigned short*)alloc((size_t)MTOT * DIM * 2);
  unsigned short* WiT  = (unsigned short*)alloc((size_t)NCOL * DIM * 2);
  unsigned short* WoT  = (unsigned short*)alloc((size_t)DIM * UV * 2);
  unsigned short* u    = (unsigned short*)alloc((size_t)MTOT * UV * 2);
  unsigned short* v    = (unsigned short*)alloc((size_t)MTOT * UV * 2);
  unsigned short* vT   = (unsigned short*)alloc((size_t)MTOT * UV * 2);
  float*          qkb  = (float*)alloc((size_t)MTOT * KEY * 4);
  unsigned short* qbuf = (unsigned short*)alloc((size_t)MTOT * KEY * 2);
  unsigned short* kbuf = (unsigned short*)alloc((size_t)MTOT * KEY * 2);
  float*          ll   = (float*)alloc((size_t)MTOT * 4);
  unsigned short* Abuf = (unsigned short*)alloc((size_t)BATCH * SEQ * SEQ * 2);
  unsigned short* g    = (unsigned short*)alloc((size_t)MTOT * UV * 2);

  k_cvt<<<(MTOT * DIM / 4) / 256, 256, 0, stream>>>(h, hbf);
  k_tcvt<<<dim3(NCOL / 32, DIM / 32), dim3(32, 8), 0, stream>>>(Wi, WiT, DIM, NCOL);
  k_tcvt<<<dim3(UV / 32, DIM / 32), dim3(32, 8), 0, stream>>>(Wo, WoT, DIM, UV);
  k_masksum<<<MTOT / 4, 256, 0, stream>>>(mask, ll);

  k_gemm1<<<dim3(MTOT / 256, NCOL / 128), 512, LDS_BYTES, stream>>>(hbf, WiT, bi, u, v, qkb);
  k_rope<<<(MTOT * 64) / 256, 256, 0, stream>>>(qkb, sn, cs, qg, qb, kg, kb, qbuf, kbuf);
  k_vT<<<dim3(SEQ / 64, UV / 64, BATCH), 256, 0, stream>>>(v, vT);
  k_qk<<<dim3(SEQ / 256, SEQ / 128, BATCH), 512, LDS_BYTES, stream>>>(qbuf, kbuf, mask, ll, Abuf);
  k_av<<<dim3(SEQ / 256, UV / 128, BATCH), 512, LDS_BYTES, stream>>>(Abuf, vT, u, g);
  k_out<<<dim3(MTOT / 256, DIM / 128), 512, LDS_BYTES, stream>>>(g, WoT, bo, out);
}

// Round 4
// 204.409 us; speedup vs baseline: 1.1587x; 1.0032x over previous
//
#include <hip/hip_runtime.h>
#include <hip/hip_bf16.h>
#include <cstdint>

#define DIM   1024
#define KEY   128
#define UV    1024
#define NCOL  (UV*2 + KEY)   // 2176
#define SEQ   2048
#define BATCH 4
#define MTOT  (BATCH*SEQ)    // 8192
#define SCALE 0.08838834764831845f  // 1/sqrt(128)

typedef __attribute__((ext_vector_type(8))) short short8;
typedef __attribute__((ext_vector_type(4))) float f32x4;

__device__ inline unsigned short f2b(float x) {
  unsigned int u = __float_as_uint(x);
  unsigned int r = (u + 0x7fffu + ((u >> 16) & 1u)) >> 16;
  return (unsigned short)r;
}
__device__ inline float b2f(unsigned short x) {
  return __uint_as_float(((unsigned int)x) << 16);
}

__device__ inline void gload_lds16(const void* g, void* l) {
  __builtin_amdgcn_global_load_lds(
      (const __attribute__((address_space(1))) unsigned int*)g,
      (__attribute__((address_space(3))) unsigned int*)l, 16, 0, 0);
}

#define BARX() do { asm volatile("" ::: "memory"); __builtin_amdgcn_s_barrier(); asm volatile("" ::: "memory"); } while (0)

// ---------------------------------------------------------------------------
// 256x128 bt-GEMM tile, 8 waves (4M x 2N), wave-tile 64x64, BK=64.
// 4-phase interleaved schedule (T3+T4): per phase {8 ds_read_b128 | stage one
// kk-half (3 gload_lds) | barrier | 16 MFMA (setprio) | barrier}; vmcnt(3)
// only at K-tile boundaries (phases 2,4).  2-buffer ring, phase-proven
// retirement (half staged in phase p was last read in phase p-1).
// LDS layout [buf][kk][rows][32] bf16: 64B row stride -> bank-parity balanced
// (conflict-free, no swizzle); kk-half linear -> direct global_load_lds.
// LDS: A 2*2*256*32 + B 2*2*128*32 elems = 96 KiB dynamic.
// ---------------------------------------------------------------------------
__device__ __forceinline__ void gemm4ph(
    const unsigned short* __restrict__ A, int lda,
    const unsigned short* __restrict__ Bt, int ldb,
    int K, f32x4 acc[4][4], unsigned short* lds) {
  const int tid  = threadIdx.x;
  const int lane = tid & 63;
  const int wid  = tid >> 6;      // 0..7
  const int wm   = wid >> 1;      // 0..3
  const int wn   = wid & 1;       // 0..1
  const int fr   = lane & 15;
  const int fq   = lane >> 4;

  unsigned short* ldsA = lds;             // [2][2][256][32] = 32768 elems
  unsigned short* ldsB = lds + 32768;     // [2][2][128][32] = 16384 elems

#pragma unroll
  for (int i = 0; i < 4; ++i)
#pragma unroll
    for (int j = 0; j < 4; ++j) acc[i][j] = (f32x4){0.f, 0.f, 0.f, 0.f};

  // stage kk-half h of K-tile t into buffer d (A: 2 rounds, B: 1 round)
  auto stA = [&](int t, int d, int h) {
    const unsigned short* g = A + (size_t)t * 64 + h * 32;
    unsigned short* l = ldsA + d * 16384 + h * 8192;
#pragma unroll
    for (int p = 0; p < 2; ++p) {
      int c = p * 512 + tid;                       // 0..1023: r=c>>2, q=c&3
      gload_lds16(g + (size_t)(c >> 2) * lda + (c & 3) * 8,
                  l + (size_t)(p * 512 + wid * 64) * 8);
    }
  };
  auto stB = [&](int t, int d, int h) {
    const unsigned short* g = Bt + (size_t)t * 64 + h * 32;
    unsigned short* l = ldsB + d * 8192 + h * 4096;
    gload_lds16(g + (size_t)(tid >> 2) * ldb + (tid & 3) * 8,
                l + (size_t)(wid * 64) * 8);
  };

  const int aoff = (wm * 64 + fr) * 32 + fq * 8;
  const int boff = (wn * 64 + fr) * 32 + fq * 8;

#define LDAB(d, h)                                                            \
  _Pragma("unroll") for (int i = 0; i < 4; ++i) {                             \
    af[i] = *(const short8*)&ldsA[(d) * 16384 + (h) * 8192 + aoff + i * 512]; \
    bf[i] = *(const short8*)&ldsB[(d) * 8192 + (h) * 4096 + boff + i * 512];  \
  }
#define MFMA16()                                                              \
  __builtin_amdgcn_s_setprio(1);                                              \
  _Pragma("unroll") for (int i = 0; i < 4; ++i)                               \
  _Pragma("unroll") for (int j = 0; j < 4; ++j)                               \
    acc[i][j] = __builtin_amdgcn_mfma_f32_16x16x32_bf16(af[i], bf[j], acc[i][j], 0, 0, 0); \
  __builtin_amdgcn_s_setprio(0);

  const int NT = K >> 6;        // K-tiles (>=2, even)
  const int NI = NT >> 1;       // iterations (2 K-tiles each)

  // prologue: Kt0 both halves, Kt1 kk0
  stA(0, 0, 0); stB(0, 0, 0);
  stA(0, 0, 1); stB(0, 0, 1);
  stA(1, 1, 0); stB(1, 1, 0);
  asm volatile("s_waitcnt vmcnt(3)" ::: "memory");   // Kt0 landed
  BARX();

  auto ktp = [&](int T, bool more) {
    short8 af[4], bf[4];
    // ph1: buf0 kk0 ; stage (T+1).kk1 -> buf1  (buf1.kk1 last read prev ph4)
    LDAB(0, 0); stA(T + 1, 1, 1); stB(T + 1, 1, 1);
    BARX(); MFMA16(); BARX();
    // ph2: buf0 kk1 ; stage (T+2).kk0 -> buf0  (buf0.kk0 last read ph1)
    LDAB(0, 1); if (more) { stA(T + 2, 0, 0); stB(T + 2, 0, 0); }
    BARX(); MFMA16();
    if (more) asm volatile("s_waitcnt vmcnt(3)" ::: "memory");
    else      asm volatile("s_waitcnt vmcnt(0)" ::: "memory");
    BARX();
    // ph3: buf1 kk0 ; stage (T+2).kk1 -> buf0  (buf0.kk1 last read ph2)
    LDAB(1, 0); if (more) { stA(T + 2, 0, 1); stB(T + 2, 0, 1); }
    BARX(); MFMA16(); BARX();
    // ph4: buf1 kk1 ; stage (T+3).kk0 -> buf1  (buf1.kk0 last read ph3)
    LDAB(1, 1); if (more) { stA(T + 3, 1, 0); stB(T + 3, 1, 0); }
    BARX(); MFMA16();
    if (more) asm volatile("s_waitcnt vmcnt(3)" ::: "memory");
    BARX();
  };
  for (int i = 0; i + 1 < NI; ++i) ktp(2 * i, true);
  ktp(2 * (NI - 1), false);
#undef LDAB
#undef MFMA16
}

// C/D mapping: row = wm*64 + i*16 + fq*4 + r ; col = wn*64 + j*16 + fr
#define EPILOGUE_COORDS()                      \
  const int lane = threadIdx.x & 63;           \
  const int wid  = threadIdx.x >> 6;           \
  const int wm   = wid >> 1, wn = wid & 1;     \
  const int fr   = lane & 15;                  \
  const int fq   = lane >> 4;

// XCD-aware bijective swizzle over a 2D grid (x-major chunks; nwg % 8 == 0)
__device__ __forceinline__ void xcd_swz(int& tx, int& ty) {
  const int gx = gridDim.x, gy = gridDim.y;
  const int n = gx * gy;
  const int D = blockIdx.y * gx + blockIdx.x;
  const int c = (D & 7) * (n >> 3) + (D >> 3);
  tx = c / gy;
  ty = c - tx * gy;
}

// ---------------------------------------------------------------------------
// helper kernels
// ---------------------------------------------------------------------------
__global__ __launch_bounds__(256) void k_cvt(const float* __restrict__ in,
                                             unsigned short* __restrict__ out) {
  int id = blockIdx.x * 256 + threadIdx.x;
  float4 f = ((const float4*)in)[id];
  ushort4 o;
  o.x = f2b(f.x); o.y = f2b(f.y); o.z = f2b(f.z); o.w = f2b(f.w);
  ((ushort4*)out)[id] = o;
}

__global__ void k_tcvt(const float* __restrict__ in, unsigned short* __restrict__ out,
                       int R, int C) {
  __shared__ float t[32][33];
  int c0 = blockIdx.x * 32, r0 = blockIdx.y * 32;
  int tx = threadIdx.x, ty = threadIdx.y;
#pragma unroll
  for (int i = 0; i < 4; ++i)
    t[ty + i * 8][tx] = in[(size_t)(r0 + ty + i * 8) * C + c0 + tx];
  __syncthreads();
#pragma unroll
  for (int i = 0; i < 4; ++i)
    out[(size_t)(c0 + ty + i * 8) * R + r0 + tx] = f2b(t[tx][ty + i * 8]);
}

// mask -> row sums (ll) + bit-packed mask (mb: [MTOT][64] u32)
__global__ __launch_bounds__(256) void k_maskprep(const int* __restrict__ mask,
                                                  float* __restrict__ ll,
                                                  unsigned int* __restrict__ mb) {
  int wid = threadIdx.x >> 6, lane = threadIdx.x & 63;
  int row = blockIdx.x * 4 + wid;
  const int4* p = (const int4*)(mask + (size_t)row * SEQ);
  int s = 0;
#pragma unroll
  for (int i = 0; i < 8; ++i) {
    int4 v = p[i * 64 + lane];
    unsigned nib = (v.x != 0 ? 1u : 0u) | (v.y != 0 ? 2u : 0u) |
                   (v.z != 0 ? 4u : 0u) | (v.w != 0 ? 8u : 0u);
    unsigned w = 0;
#pragma unroll
    for (int k2 = 0; k2 < 8; ++k2)
      w |= __shfl(nib, (lane & ~7) + k2, 64) << (4 * k2);
    if ((lane & 7) == 0) mb[(size_t)row * 64 + i * 8 + (lane >> 3)] = w;
    s += v.x + v.y + v.z + v.w;
  }
  for (int off = 32; off; off >>= 1) s += __shfl_down(s, off);
  if (lane == 0) ll[row] = (float)s;
}

__global__ __launch_bounds__(256) void k_rope(const float* __restrict__ qk,
                                              const float* __restrict__ sn,
                                              const float* __restrict__ cs,
                                              const float* __restrict__ qg,
                                              const float* __restrict__ qb,
                                              const float* __restrict__ kg,
                                              const float* __restrict__ kb,
                                              unsigned short* __restrict__ q,
                                              unsigned short* __restrict__ k) {
  int id = blockIdx.x * 256 + threadIdx.x;
  int m = id >> 6, t = id & 63;
  int n = m & (SEQ - 1);
  float x1 = qk[m * KEY + 2 * t], x2 = qk[m * KEY + 2 * t + 1];
  float s_ = sn[n * 64 + t], c_ = cs[n * 64 + t];
  float a1 = x1 * qg[2 * t] + qb[2 * t];
  float a2 = x2 * qg[2 * t + 1] + qb[2 * t + 1];
  q[m * KEY + t]      = f2b(a1 * c_ - a2 * s_);
  q[m * KEY + 64 + t] = f2b(a1 * s_ + a2 * c_);
  float b1 = x1 * kg[2 * t] + kb[2 * t];
  float b2 = x2 * kg[2 * t + 1] + kb[2 * t + 1];
  k[m * KEY + t]      = f2b(b1 * c_ - b2 * s_);
  k[m * KEY + 64 + t] = f2b(b1 * s_ + b2 * c_);
}

__global__ __launch_bounds__(256) void k_vT(const unsigned short* __restrict__ v,
                                            unsigned short* __restrict__ vT) {
  __shared__ unsigned short t[64][65];
  int b = blockIdx.z;
  int n0 = blockIdx.x * 64;
  int d0 = blockIdx.y * 64;
  int tid = threadIdx.x;
  int r = tid >> 4;
  int c4 = (tid & 15) * 4;
#pragma unroll
  for (int i = 0; i < 4; ++i) {
    int n = n0 + r + i * 16;
    ushort4 val = *(const ushort4*)&v[((size_t)b * SEQ + n) * UV + d0 + c4];
    t[c4 + 0][r + i * 16] = val.x;
    t[c4 + 1][r + i * 16] = val.y;
    t[c4 + 2][r + i * 16] = val.z;
    t[c4 + 3][r + i * 16] = val.w;
  }
  __syncthreads();
#pragma unroll
  for (int i = 0; i < 4; ++i) {
    int d = d0 + r + i * 16;
    ushort4 o;
    o.x = t[r + i * 16][c4 + 0];
    o.y = t[r + i * 16][c4 + 1];
    o.z = t[r + i * 16][c4 + 2];
    o.w = t[r + i * 16][c4 + 3];
    *(ushort4*)&vT[((size_t)b * UV + d) * SEQ + n0 + c4] = o;
  }
}

// ---------------------------------------------------------------------------
// GEMM kernels (256x128 tiles, 512 threads, 96 KiB dynamic LDS)
// ---------------------------------------------------------------------------
#define LDS_BYTES 98304

__global__ __launch_bounds__(512, 2) void k_gemm1(const unsigned short* __restrict__ hbf,
                                                  const unsigned short* __restrict__ WiT,
                                                  const float* __restrict__ bi,
                                                  unsigned short* __restrict__ u,
                                                  unsigned short* __restrict__ v,
                                                  float* __restrict__ qk) {
  extern __shared__ unsigned short lds[];
  int tx, ty; xcd_swz(tx, ty);
  int m0 = tx * 256, n0 = ty * 128;
  f32x4 acc[4][4];
  gemm4ph(hbf + (size_t)m0 * DIM, DIM, WiT + (size_t)n0 * DIM, DIM, DIM, acc, lds);
  EPILOGUE_COORDS();
#pragma unroll
  for (int i = 0; i < 4; ++i)
#pragma unroll
    for (int j = 0; j < 4; ++j)
#pragma unroll
      for (int r = 0; r < 4; ++r) {
        int row = m0 + wm * 64 + i * 16 + fq * 4 + r;
        int col = n0 + wn * 64 + j * 16 + fr;
        float x = acc[i][j][r] + bi[col];
        float s = x / (1.f + __expf(-x));
        if (n0 < UV)            u[(size_t)row * UV + col] = f2b(s);
        else if (n0 < 2 * UV)   v[(size_t)row * UV + col - UV] = f2b(s);
        else                    qk[(size_t)row * KEY + col - 2 * UV] = s;
      }
}

__global__ __launch_bounds__(512, 2) void k_qk(const unsigned short* __restrict__ q,
                                               const unsigned short* __restrict__ k,
                                               const unsigned int* __restrict__ mb,
                                               const float* __restrict__ ll,
                                               unsigned short* __restrict__ Abuf) {
  extern __shared__ unsigned short lds[];
  int b = blockIdx.z;
  int tx, ty; xcd_swz(tx, ty);
  int m0 = tx * 256, n0 = ty * 128;
  f32x4 acc[4][4];
  gemm4ph(q + ((size_t)b * SEQ + m0) * KEY, KEY,
          k + ((size_t)b * SEQ + n0) * KEY, KEY, KEY, acc, lds);
  EPILOGUE_COORDS();
#pragma unroll
  for (int i = 0; i < 4; ++i)
#pragma unroll
    for (int r = 0; r < 4; ++r) {
      int row = m0 + wm * 64 + i * 16 + fq * 4 + r;
      size_t rb = (size_t)b * SEQ + row;
      unsigned long long mw =
          *(const unsigned long long*)&mb[rb * 64 + (n0 >> 5) + wn * 2];
      float rll = 1.0f / ll[rb];
#pragma unroll
      for (int j = 0; j < 4; ++j) {
        int col = n0 + wn * 64 + j * 16 + fr;
        float a = acc[i][j][r] * SCALE;
        bool on = (mw >> (j * 16 + fr)) & 1ull;
        float rel = (on && a > 0.f) ? a : 0.f;
        Abuf[rb * SEQ + col] = f2b(rel * rel * rll);
      }
    }
}

__global__ __launch_bounds__(512, 2) void k_av(const unsigned short* __restrict__ Abuf,
                                               const unsigned short* __restrict__ vT,
                                               const unsigned short* __restrict__ u,
                                               unsigned short* __restrict__ g) {
  extern __shared__ unsigned short lds[];
  int b = blockIdx.z;
  int tx, ty; xcd_swz(tx, ty);
  int m0 = tx * 256, n0 = ty * 128;
  f32x4 acc[4][4];
  gemm4ph(Abuf + ((size_t)b * SEQ + m0) * SEQ, SEQ,
          vT + ((size_t)b * UV + n0) * SEQ, SEQ, SEQ, acc, lds);
  EPILOGUE_COORDS();
#pragma unroll
  for (int i = 0; i < 4; ++i)
#pragma unroll
    for (int j = 0; j < 4; ++j)
#pragma unroll
      for (int r = 0; r < 4; ++r) {
        int row = m0 + wm * 64 + i * 16 + fq * 4 + r;
        int col = n0 + wn * 64 + j * 16 + fr;
        size_t gi = ((size_t)b * SEQ + row) * UV + col;
        g[gi] = f2b(acc[i][j][r] * b2f(u[gi]));
      }
}

__global__ __launch_bounds__(512, 2) void k_out(const unsigned short* __restrict__ g,
                                                const unsigned short* __restrict__ WoT,
                                                const float* __restrict__ bo,
                                                float* __restrict__ out) {
  extern __shared__ unsigned short lds[];
  int tx, ty; xcd_swz(tx, ty);
  int m0 = tx * 256, n0 = ty * 128;
  f32x4 acc[4][4];
  gemm4ph(g + (size_t)m0 * UV, UV, WoT + (size_t)n0 * UV, UV, UV, acc, lds);
  EPILOGUE_COORDS();
#pragma unroll
  for (int i = 0; i < 4; ++i)
#pragma unroll
    for (int j = 0; j < 4; ++j)
#pragma unroll
      for (int r = 0; r < 4; ++r) {
        int row = m0 + wm * 64 + i * 16 + fq * 4 + r;
        int col = n0 + wn * 64 + j * 16 + fr;
        out[(size_t)row * DIM + col] = acc[i][j][r] + bo[col];
      }
}

// ---------------------------------------------------------------------------
extern "C" void kernel_launch(void* const* d_in, const int* in_sizes, int n_in,
                              void* d_out, int out_size, void* d_ws, size_t ws_size,
                              hipStream_t stream) {
  const float* h    = (const float*)d_in[0];
  const int*   mask = (const int*)d_in[1];
  const float* sn   = (const float*)d_in[2];
  const float* cs   = (const float*)d_in[3];
  const float* Wi   = (const float*)d_in[4];
  const float* bi   = (const float*)d_in[5];
  const float* Wo   = (const float*)d_in[6];
  const float* bo   = (const float*)d_in[7];
  const float* qg   = (const float*)d_in[8];
  const float* qb   = (const float*)d_in[9];
  const float* kg   = (const float*)d_in[10];
  const float* kb   = (const float*)d_in[11];
  float* out = (float*)d_out;

  hipFuncSetAttribute((const void*)k_gemm1, hipFuncAttributeMaxDynamicSharedMemorySize, LDS_BYTES);
  hipFuncSetAttribute((const void*)k_qk,    hipFuncAttributeMaxDynamicSharedMemorySize, LDS_BYTES);
  hipFuncSetAttribute((const void*)k_av,    hipFuncAttributeMaxDynamicSharedMemorySize, LDS_BYTES);
  hipFuncSetAttribute((const void*)k_out,   hipFuncAttributeMaxDynamicSharedMemorySize, LDS_BYTES);

  char* ws = (char*)d_ws;
  size_t off = 0;
  auto alloc = [&](size_t bytes) { void* p = ws + off; off += (bytes + 255) & ~(size_t)255; return p; };
  unsigned short* hbf  = (unsigned short*)alloc((size_t)MTOT * DIM * 2);
  unsigned short* WiT  = (unsigned short*)alloc((size_t)NCOL * DIM * 2);
  unsigned short* WoT  = (unsigned short*)alloc((size_t)DIM * UV * 2);
  unsigned short* u    = (unsigned short*)alloc((size_t)MTOT * UV * 2);
  unsigned short* v    = (unsigned short*)alloc((size_t)MTOT * UV * 2);
  unsigned short* vT   = (unsigned short*)alloc((size_t)MTOT * UV * 2);
  float*          qkb  = (float*)alloc((size_t)MTOT * KEY * 4);
  unsigned short* qbuf = (unsigned short*)alloc((size_t)MTOT * KEY * 2);
  unsigned short* kbuf = (unsigned short*)alloc((size_t)MTOT * KEY * 2);
  float*          ll   = (float*)alloc((size_t)MTOT * 4);
  unsigned int*   mbits= (unsigned int*)alloc((size_t)MTOT * 64 * 4);
  unsigned short* Abuf = (unsigned short*)alloc((size_t)BATCH * SEQ * SEQ * 2);
  unsigned short* g    = (unsigned short*)alloc((size_t)MTOT * UV * 2);

  k_cvt<<<(MTOT * DIM / 4) / 256, 256, 0, stream>>>(h, hbf);
  k_tcvt<<<dim3(NCOL / 32, DIM / 32), dim3(32, 8), 0, stream>>>(Wi, WiT, DIM, NCOL);
  k_tcvt<<<dim3(UV / 32, DIM / 32), dim3(32, 8), 0, stream>>>(Wo, WoT, DIM, UV);
  k_maskprep<<<MTOT / 4, 256, 0, stream>>>(mask, ll, mbits);

  k_gemm1<<<dim3(MTOT / 256, NCOL / 128), 512, LDS_BYTES, stream>>>(hbf, WiT, bi, u, v, qkb);
  k_rope<<<(MTOT * 64) / 256, 256, 0, stream>>>(qkb, sn, cs, qg, qb, kg, kb, qbuf, kbuf);
  k_vT<<<dim3(SEQ / 64, UV / 64, BATCH), 256, 0, stream>>>(v, vT);
  k_qk<<<dim3(SEQ / 256, SEQ / 128, BATCH), 512, LDS_BYTES, stream>>>(qbuf, kbuf, mbits, ll, Abuf);
  k_av<<<dim3(SEQ / 256, UV / 128, BATCH), 512, LDS_BYTES, stream>>>(Abuf, vT, u, g);
  k_out<<<dim3(MTOT / 256, DIM / 128), 512, LDS_BYTES, stream>>>(g, WoT, bo, out);
}

// Round 6
// 190.167 us; speedup vs baseline: 1.2455x; 1.0749x over previous
//
#include <hip/hip_runtime.h>
#include <hip/hip_bf16.h>
#include <cstdint>

#define DIM   1024
#define KEY   128
#define UV    1024
#define NCOL  (UV*2 + KEY)   // 2176
#define SEQ   2048
#define BATCH 4
#define MTOT  (BATCH*SEQ)    // 8192
#define SCALE 0.08838834764831845f  // 1/sqrt(128)

typedef __attribute__((ext_vector_type(8))) short short8;
typedef __attribute__((ext_vector_type(4))) float f32x4;

__device__ inline unsigned short f2b(float x) {
  unsigned int u = __float_as_uint(x);
  unsigned int r = (u + 0x7fffu + ((u >> 16) & 1u)) >> 16;
  return (unsigned short)r;
}
__device__ inline float b2f(unsigned short x) {
  return __uint_as_float(((unsigned int)x) << 16);
}

__device__ inline void gload_lds16(const void* g, void* l) {
  __builtin_amdgcn_global_load_lds(
      (const __attribute__((address_space(1))) unsigned int*)g,
      (__attribute__((address_space(3))) unsigned int*)l, 16, 0, 0);
}

// ---------------------------------------------------------------------------
// 128x128 bt-GEMM tile, 4 waves (2x2), wave-tile 64x64, BK=32, double-buffered
// with counted vmcnt(4) (= loads-per-stage, 1 stage in flight).
// C[m][n] = sum_k A[m][k]*Bt[n][k].
// LDS [2 buf][A 128x32 | B 128x32] = 32 KiB -> 4 blocks/CU.
// Conflict-free slot swizzle: LDS(r, q) = G(r, q ^ ((r>>1)&3))  (16B slots);
// read slot = fq ^ ((fr>>1)&3): per 16-lane group bank start
// (r&1)*16 + 4*((r>>1)&3) covers all 32 banks exactly twice (b128 minimum).
// ---------------------------------------------------------------------------
__device__ __forceinline__ void gemm128(
    const unsigned short* __restrict__ A, int lda,
    const unsigned short* __restrict__ Bt, int ldb,
    int K, f32x4 acc[4][4], unsigned short* lds) {
  const int tid  = threadIdx.x;
  const int lane = tid & 63;
  const int wid  = tid >> 6;      // 0..3
  const int wr   = wid >> 1, wc = wid & 1;
  const int fr   = lane & 15;
  const int fq   = lane >> 4;

#pragma unroll
  for (int i = 0; i < 4; ++i)
#pragma unroll
    for (int j = 0; j < 4; ++j) acc[i][j] = (f32x4){0.f, 0.f, 0.f, 0.f};

  // buffers: lds + d*8192 : [A 4096][B 4096] elems
  // stage K-step k into buffer d: A 2 rounds + B 2 rounds = 4 gloads/thread
  auto stage = [&](int k, int d) {
    unsigned short* la = lds + d * 8192;
    unsigned short* lb = la + 4096;
#pragma unroll
    for (int p = 0; p < 2; ++p) {
      int c = p * 256 + tid;          // 0..511: r = c>>2, q = c&3
      int r = c >> 2, q = c & 3;
      int qs = q ^ ((r >> 1) & 3);    // pre-swizzled source
      gload_lds16(A + (size_t)r * lda + k * 32 + qs * 8,
                  la + (size_t)(p * 256 + wid * 64) * 8);
    }
#pragma unroll
    for (int p = 0; p < 2; ++p) {
      int c = p * 256 + tid;
      int r = c >> 2, q = c & 3;
      int qs = q ^ ((r >> 1) & 3);
      gload_lds16(Bt + (size_t)r * ldb + k * 32 + qs * 8,
                  lb + (size_t)(p * 256 + wid * 64) * 8);
    }
  };

  const int slot = (fq ^ ((fr >> 1) & 3)) * 8;
  const int rA   = (wr * 64 + fr) * 32 + slot;   // + i*512
  const int rB   = (wc * 64 + fr) * 32 + slot;   // + j*512

  const int NK = K >> 5;
  stage(0, 0);
  for (int k = 0; k < NK; ++k) {
    const int d = k & 1;
    if (k + 1 < NK) {
      stage(k + 1, d ^ 1);
      asm volatile("s_waitcnt vmcnt(4)" ::: "memory");  // stage(k)'s 4 landed;
                                                        // stage(k+1)'s 4 in flight
    } else {
      asm volatile("s_waitcnt vmcnt(0)" ::: "memory");
    }
    __builtin_amdgcn_s_barrier();
    asm volatile("" ::: "memory");
    const unsigned short* la = lds + d * 8192;
    const unsigned short* lb = la + 4096;
    short8 af[4], bf[4];
#pragma unroll
    for (int s = 0; s < 4; ++s) {
      af[s] = *(const short8*)&la[rA + s * 512];
      bf[s] = *(const short8*)&lb[rB + s * 512];
    }
#pragma unroll
    for (int i = 0; i < 4; ++i)
#pragma unroll
      for (int j = 0; j < 4; ++j)
        acc[i][j] = __builtin_amdgcn_mfma_f32_16x16x32_bf16(af[i], bf[j], acc[i][j], 0, 0, 0);
    asm volatile("" ::: "memory");
    __builtin_amdgcn_s_barrier();   // reads of buf d done; next iter may overwrite
    asm volatile("" ::: "memory");
  }
}

// C/D mapping: row = wr*64 + i*16 + fq*4 + r ; col = wc*64 + j*16 + fr
#define EPILOGUE_COORDS()                      \
  const int lane = threadIdx.x & 63;           \
  const int wid  = threadIdx.x >> 6;           \
  const int wr   = wid >> 1, wc = wid & 1;     \
  const int fr   = lane & 15;                  \
  const int fq   = lane >> 4;

// XCD-aware bijective swizzle over a 2D grid (requires gx*gy % 8 == 0)
__device__ __forceinline__ void xcd_swz(int& tx, int& ty) {
  const int gx = gridDim.x, gy = gridDim.y;
  const int n = gx * gy;
  const int D = blockIdx.y * gx + blockIdx.x;
  const int c = (D & 7) * (n >> 3) + (D >> 3);
  tx = c / gy;
  ty = c - tx * gy;
}

// ---------------------------------------------------------------------------
// helper kernels
// ---------------------------------------------------------------------------
__global__ __launch_bounds__(256) void k_cvt(const float* __restrict__ in,
                                             unsigned short* __restrict__ out) {
  int id = blockIdx.x * 256 + threadIdx.x;
  float4 f = ((const float4*)in)[id];
  ushort4 o;
  o.x = f2b(f.x); o.y = f2b(f.y); o.z = f2b(f.z); o.w = f2b(f.w);
  ((ushort4*)out)[id] = o;
}

__global__ void k_tcvt(const float* __restrict__ in, unsigned short* __restrict__ out,
                       int R, int C) {
  __shared__ float t[32][33];
  int c0 = blockIdx.x * 32, r0 = blockIdx.y * 32;
  int tx = threadIdx.x, ty = threadIdx.y;
#pragma unroll
  for (int i = 0; i < 4; ++i)
    t[ty + i * 8][tx] = in[(size_t)(r0 + ty + i * 8) * C + c0 + tx];
  __syncthreads();
#pragma unroll
  for (int i = 0; i < 4; ++i)
    out[(size_t)(c0 + ty + i * 8) * R + r0 + tx] = f2b(t[tx][ty + i * 8]);
}

// mask -> row sums (ll) + bit-packed mask (mb: [MTOT][64] u32)
__global__ __launch_bounds__(256) void k_maskprep(const int* __restrict__ mask,
                                                  float* __restrict__ ll,
                                                  unsigned int* __restrict__ mb) {
  int wid = threadIdx.x >> 6, lane = threadIdx.x & 63;
  int row = blockIdx.x * 4 + wid;
  const int4* p = (const int4*)(mask + (size_t)row * SEQ);
  int s = 0;
#pragma unroll
  for (int i = 0; i < 8; ++i) {
    int4 v = p[i * 64 + lane];
    unsigned nib = (v.x != 0 ? 1u : 0u) | (v.y != 0 ? 2u : 0u) |
                   (v.z != 0 ? 4u : 0u) | (v.w != 0 ? 8u : 0u);
    unsigned w = 0;
#pragma unroll
    for (int k2 = 0; k2 < 8; ++k2)
      w |= __shfl(nib, (lane & ~7) + k2, 64) << (4 * k2);
    if ((lane & 7) == 0) mb[(size_t)row * 64 + i * 8 + (lane >> 3)] = w;
    s += v.x + v.y + v.z + v.w;
  }
  for (int off = 32; off; off >>= 1) s += __shfl_down(s, off);
  if (lane == 0) ll[row] = (float)s;
}

__global__ __launch_bounds__(256) void k_rope(const float* __restrict__ qk,
                                              const float* __restrict__ sn,
                                              const float* __restrict__ cs,
                                              const float* __restrict__ qg,
                                              const float* __restrict__ qb,
                                              const float* __restrict__ kg,
                                              const float* __restrict__ kb,
                                              unsigned short* __restrict__ q,
                                              unsigned short* __restrict__ k) {
  int id = blockIdx.x * 256 + threadIdx.x;
  int m = id >> 6, t = id & 63;
  int n = m & (SEQ - 1);
  float x1 = qk[m * KEY + 2 * t], x2 = qk[m * KEY + 2 * t + 1];
  float s_ = sn[n * 64 + t], c_ = cs[n * 64 + t];
  float a1 = x1 * qg[2 * t] + qb[2 * t];
  float a2 = x2 * qg[2 * t + 1] + qb[2 * t + 1];
  q[m * KEY + t]      = f2b(a1 * c_ - a2 * s_);
  q[m * KEY + 64 + t] = f2b(a1 * s_ + a2 * c_);
  float b1 = x1 * kg[2 * t] + kb[2 * t];
  float b2 = x2 * kg[2 * t + 1] + kb[2 * t + 1];
  k[m * KEY + t]      = f2b(b1 * c_ - b2 * s_);
  k[m * KEY + 64 + t] = f2b(b1 * s_ + b2 * c_);
}

__global__ __launch_bounds__(256) void k_vT(const unsigned short* __restrict__ v,
                                            unsigned short* __restrict__ vT) {
  __shared__ unsigned short t[64][65];
  int b = blockIdx.z;
  int n0 = blockIdx.x * 64;
  int d0 = blockIdx.y * 64;
  int tid = threadIdx.x;
  int r = tid >> 4;
  int c4 = (tid & 15) * 4;
#pragma unroll
  for (int i = 0; i < 4; ++i) {
    int n = n0 + r + i * 16;
    ushort4 val = *(const ushort4*)&v[((size_t)b * SEQ + n) * UV + d0 + c4];
    t[c4 + 0][r + i * 16] = val.x;
    t[c4 + 1][r + i * 16] = val.y;
    t[c4 + 2][r + i * 16] = val.z;
    t[c4 + 3][r + i * 16] = val.w;
  }
  __syncthreads();
#pragma unroll
  for (int i = 0; i < 4; ++i) {
    int d = d0 + r + i * 16;
    ushort4 o;
    o.x = t[r + i * 16][c4 + 0];
    o.y = t[r + i * 16][c4 + 1];
    o.z = t[r + i * 16][c4 + 2];
    o.w = t[r + i * 16][c4 + 3];
    *(ushort4*)&vT[((size_t)b * UV + d) * SEQ + n0 + c4] = o;
  }
}

// ---------------------------------------------------------------------------
// GEMM kernels (128x128 tiles, 256 threads, 32 KiB static LDS, 4 blocks/CU)
// ---------------------------------------------------------------------------
__global__ __launch_bounds__(256, 4) void k_gemm1(const unsigned short* __restrict__ hbf,
                                                  const unsigned short* __restrict__ WiT,
                                                  const float* __restrict__ bi,
                                                  unsigned short* __restrict__ u,
                                                  unsigned short* __restrict__ v,
                                                  float* __restrict__ qk) {
  __shared__ unsigned short lds[16384];
  int tx, ty; xcd_swz(tx, ty);
  int m0 = tx * 128, n0 = ty * 128;
  f32x4 acc[4][4];
  gemm128(hbf + (size_t)m0 * DIM, DIM, WiT + (size_t)n0 * DIM, DIM, DIM, acc, lds);
  EPILOGUE_COORDS();
#pragma unroll
  for (int i = 0; i < 4; ++i)
#pragma unroll
    for (int j = 0; j < 4; ++j)
#pragma unroll
      for (int r = 0; r < 4; ++r) {
        int row = m0 + wr * 64 + i * 16 + fq * 4 + r;
        int col = n0 + wc * 64 + j * 16 + fr;
        float x = acc[i][j][r] + bi[col];
        float s = x / (1.f + __expf(-x));
        if (n0 < UV)            u[(size_t)row * UV + col] = f2b(s);
        else if (n0 < 2 * UV)   v[(size_t)row * UV + col - UV] = f2b(s);
        else                    qk[(size_t)row * KEY + col - 2 * UV] = s;
      }
}

__global__ __launch_bounds__(256, 4) void k_qk(const unsigned short* __restrict__ q,
                                               const unsigned short* __restrict__ k,
                                               const unsigned int* __restrict__ mb,
                                               const float* __restrict__ ll,
                                               unsigned short* __restrict__ Abuf) {
  __shared__ unsigned short lds[16384];
  int b = blockIdx.z;
  int tx, ty; xcd_swz(tx, ty);
  int m0 = tx * 128, n0 = ty * 128;
  f32x4 acc[4][4];
  gemm128(q + ((size_t)b * SEQ + m0) * KEY, KEY,
          k + ((size_t)b * SEQ + n0) * KEY, KEY, KEY, acc, lds);
  EPILOGUE_COORDS();
#pragma unroll
  for (int i = 0; i < 4; ++i)
#pragma unroll
    for (int r = 0; r < 4; ++r) {
      int row = m0 + wr * 64 + i * 16 + fq * 4 + r;
      size_t rb = (size_t)b * SEQ + row;
      unsigned long long mw =
          *(const unsigned long long*)&mb[rb * 64 + (n0 >> 5) + wc * 2];
      float rll = 1.0f / ll[rb];
#pragma unroll
      for (int j = 0; j < 4; ++j) {
        int col = n0 + wc * 64 + j * 16 + fr;
        float a = acc[i][j][r] * SCALE;
        bool on = (mw >> (j * 16 + fr)) & 1ull;
        float rel = (on && a > 0.f) ? a : 0.f;
        Abuf[rb * SEQ + col] = f2b(rel * rel * rll);
      }
    }
}

__global__ __launch_bounds__(256, 4) void k_av(const unsigned short* __restrict__ Abuf,
                                               const unsigned short* __restrict__ vT,
                                               const unsigned short* __restrict__ u,
                                               unsigned short* __restrict__ g) {
  __shared__ unsigned short lds[16384];
  int b = blockIdx.z;
  int tx, ty; xcd_swz(tx, ty);
  int m0 = tx * 128, n0 = ty * 128;
  f32x4 acc[4][4];
  gemm128(Abuf + ((size_t)b * SEQ + m0) * SEQ, SEQ,
          vT + ((size_t)b * UV + n0) * SEQ, SEQ, SEQ, acc, lds);
  EPILOGUE_COORDS();
#pragma unroll
  for (int i = 0; i < 4; ++i)
#pragma unroll
    for (int j = 0; j < 4; ++j)
#pragma unroll
      for (int r = 0; r < 4; ++r) {
        int row = m0 + wr * 64 + i * 16 + fq * 4 + r;
        int col = n0 + wc * 64 + j * 16 + fr;
        size_t gi = ((size_t)b * SEQ + row) * UV + col;
        g[gi] = f2b(acc[i][j][r] * b2f(u[gi]));
      }
}

__global__ __launch_bounds__(256, 4) void k_out(const unsigned short* __restrict__ g,
                                                const unsigned short* __restrict__ WoT,
                                                const float* __restrict__ bo,
                                                float* __restrict__ out) {
  __shared__ unsigned short lds[16384];
  int tx, ty; xcd_swz(tx, ty);
  int m0 = tx * 128, n0 = ty * 128;
  f32x4 acc[4][4];
  gemm128(g + (size_t)m0 * UV, UV, WoT + (size_t)n0 * UV, UV, UV, acc, lds);
  EPILOGUE_COORDS();
#pragma unroll
  for (int i = 0; i < 4; ++i)
#pragma unroll
    for (int j = 0; j < 4; ++j)
#pragma unroll
      for (int r = 0; r < 4; ++r) {
        int row = m0 + wr * 64 + i * 16 + fq * 4 + r;
        int col = n0 + wc * 64 + j * 16 + fr;
        out[(size_t)row * DIM + col] = acc[i][j][r] + bo[col];
      }
}

// ---------------------------------------------------------------------------
extern "C" void kernel_launch(void* const* d_in, const int* in_sizes, int n_in,
                              void* d_out, int out_size, void* d_ws, size_t ws_size,
                              hipStream_t stream) {
  const float* h    = (const float*)d_in[0];
  const int*   mask = (const int*)d_in[1];
  const float* sn   = (const float*)d_in[2];
  const float* cs   = (const float*)d_in[3];
  const float* Wi   = (const float*)d_in[4];
  const float* bi   = (const float*)d_in[5];
  const float* Wo   = (const float*)d_in[6];
  const float* bo   = (const float*)d_in[7];
  const float* qg   = (const float*)d_in[8];
  const float* qb   = (const float*)d_in[9];
  const float* kg   = (const float*)d_in[10];
  const float* kb   = (const float*)d_in[11];
  float* out = (float*)d_out;

  char* ws = (char*)d_ws;
  size_t off = 0;
  auto alloc = [&](size_t bytes) { void* p = ws + off; off += (bytes + 255) & ~(size_t)255; return p; };
  unsigned short* hbf  = (unsigned short*)alloc((size_t)MTOT * DIM * 2);
  unsigned short* WiT  = (unsigned short*)alloc((size_t)NCOL * DIM * 2);
  unsigned short* WoT  = (unsigned short*)alloc((size_t)DIM * UV * 2);
  unsigned short* u    = (unsigned short*)alloc((size_t)MTOT * UV * 2);
  unsigned short* v    = (unsigned short*)alloc((size_t)MTOT * UV * 2);
  unsigned short* vT   = (unsigned short*)alloc((size_t)MTOT * UV * 2);
  float*          qkb  = (float*)alloc((size_t)MTOT * KEY * 4);
  unsigned short* qbuf = (unsigned short*)alloc((size_t)MTOT * KEY * 2);
  unsigned short* kbuf = (unsigned short*)alloc((size_t)MTOT * KEY * 2);
  float*          ll   = (float*)alloc((size_t)MTOT * 4);
  unsigned int*   mbits= (unsigned int*)alloc((size_t)MTOT * 64 * 4);
  unsigned short* Abuf = (unsigned short*)alloc((size_t)BATCH * SEQ * SEQ * 2);
  unsigned short* g    = (unsigned short*)alloc((size_t)MTOT * UV * 2);

  k_cvt<<<(MTOT * DIM / 4) / 256, 256, 0, stream>>>(h, hbf);
  k_tcvt<<<dim3(NCOL / 32, DIM / 32), dim3(32, 8), 0, stream>>>(Wi, WiT, DIM, NCOL);
  k_tcvt<<<dim3(UV / 32, DIM / 32), dim3(32, 8), 0, stream>>>(Wo, WoT, DIM, UV);
  k_maskprep<<<MTOT / 4, 256, 0, stream>>>(mask, ll, mbits);

  k_gemm1<<<dim3(MTOT / 128, NCOL / 128), 256, 0, stream>>>(hbf, WiT, bi, u, v, qkb);
  k_rope<<<(MTOT * 64) / 256, 256, 0, stream>>>(qkb, sn, cs, qg, qb, kg, kb, qbuf, kbuf);
  k_vT<<<dim3(SEQ / 64, UV / 64, BATCH), 256, 0, stream>>>(v, vT);
  k_qk<<<dim3(SEQ / 128, SEQ / 128, BATCH), 256, 0, stream>>>(qbuf, kbuf, mbits, ll, Abuf);
  k_av<<<dim3(SEQ / 128, UV / 128, BATCH), 256, 0, stream>>>(Abuf, vT, u, g);
  k_out<<<dim3(MTOT / 128, DIM / 128), 256, 0, stream>>>(g, WoT, bo, out);
}